// Round 12
// baseline (74.040 us; speedup 1.0000x reference)
//
#include <hip/hip_runtime.h>
#include <hip/hip_bf16.h>

typedef __bf16 bf16_t;
typedef __bf16 bf16x8 __attribute__((ext_vector_type(8)));
typedef float f32x4 __attribute__((ext_vector_type(4)));
typedef float f32x8 __attribute__((ext_vector_type(8)));
typedef float f32x16 __attribute__((ext_vector_type(16)));
typedef unsigned uint2v __attribute__((ext_vector_type(2)));

#define MFMA16(a, b, c) __builtin_amdgcn_mfma_f32_16x16x32_bf16((a), (b), (c), 0, 0, 0)
#define MFMA32(a, b, c) __builtin_amdgcn_mfma_f32_32x32x16_bf16((a), (b), (c), 0, 0, 0)

static constexpr int BB = 4, SS = 1024, HH = 1024, NHEAD = 16, HDIM = 64;
static constexpr int MM = BB * SS;  // 4096

__device__ __forceinline__ void gload_lds16(const void* g, void* l) {
  __builtin_amdgcn_global_load_lds((const __attribute__((address_space(1))) void*)g,
                                   (__attribute__((address_space(3))) void*)l, 16, 0, 0);
}

#if __has_builtin(__builtin_amdgcn_permlane32_swap)
#define PSWAP(a, b)                                                    \
  {                                                                    \
    uint2v _r = __builtin_amdgcn_permlane32_swap((a), (b), false, false); \
    (a) = _r.x;                                                        \
    (b) = _r.y;                                                        \
  }
#else
#define PSWAP(a, b) asm("v_permlane32_swap_b32 %0, %1" : "+v"(a), "+v"(b))
#endif

__device__ __forceinline__ float EXP2(float x) {
  float r;
  asm("v_exp_f32 %0, %1" : "=v"(r) : "v"(x));
  return r;
}

// ---------------- prep: fp32->bf16 cvt (hidden) + W transpose, one launch ----------------
__global__ __launch_bounds__(256) void prep_kernel(const float* __restrict__ hs,
                                                   const float* __restrict__ Wq,
                                                   const float* __restrict__ Wk,
                                                   const float* __restrict__ Wv,
                                                   bf16_t* __restrict__ hiddenB,
                                                   bf16_t* __restrict__ WT) {
  const int t = threadIdx.x;
  if (blockIdx.x < 2048) {
    int i = (blockIdx.x * 256 + t) * 8;
    float4 a = *(const float4*)(hs + i);
    float4 b = *(const float4*)(hs + i + 4);
    union { int4 i4; bf16_t h[8]; } u;
    u.h[0] = (bf16_t)a.x; u.h[1] = (bf16_t)a.y; u.h[2] = (bf16_t)a.z; u.h[3] = (bf16_t)a.w;
    u.h[4] = (bf16_t)b.x; u.h[5] = (bf16_t)b.y; u.h[6] = (bf16_t)b.z; u.h[7] = (bf16_t)b.w;
    *(int4*)(hiddenB + i) = u.i4;
  } else {
    __shared__ float tile[32][33];
    int id = blockIdx.x - 2048;       // 0..3071
    int z = id >> 10;                 // 0..2
    int rem = id & 1023;
    int bx = rem & 31, by = rem >> 5;
    const float* W = (z == 0) ? Wq : (z == 1) ? Wk : Wv;
    bf16_t* Out = WT + (size_t)z * HH * HH;
    int tx = t & 31, ty = t >> 5;     // 32 x 8
    int x0 = bx * 32;                 // n
    int y0 = by * 32;                 // k
    for (int j = ty; j < 32; j += 8)
      tile[j][tx] = W[(size_t)(y0 + j) * HH + x0 + tx];
    __syncthreads();
    for (int j = ty; j < 32; j += 8)
      Out[(size_t)(x0 + j) * HH + y0 + tx] = (bf16_t)tile[tx][j];
  }
}

// ---------------- QKV GEMM v3: counted-vmcnt 2-buf pipeline ----------------
// BM=128 x BN=384, BK=64, 256 blocks (1/CU), 8 waves. Per K-tile j:
//   ds_read ALL frags of tile j -> regs; lgkmcnt(0); barrier;
//   issue stage(j+2) into buf[j&1] (just-freed); 48-MFMA burst;
//   vmcnt(8) (wait stage(j+1) only -- stage(j+2) stays in flight); barrier.
// Loads are never drained to 0 mid-loop: HBM latency overlaps the next tile.
#define BMT 128
#define BNT 384
#define BKT 64
#define NTL 16
#define BUFBYTES 65536  // (128+384)*64*2

__global__ __launch_bounds__(512, 2) void qkv_gemm3(const bf16_t* __restrict__ hiddenB,
                                                    const bf16_t* __restrict__ WT,
                                                    const float* __restrict__ bq,
                                                    const float* __restrict__ bk,
                                                    const float* __restrict__ bv,
                                                    bf16_t* __restrict__ Qo,
                                                    bf16_t* __restrict__ Ko,
                                                    bf16_t* __restrict__ Vt) {
  __shared__ bf16_t smem[2 * BUFBYTES / 2];  // 128 KB

  // XCD swizzle: 256 wgs = 8 XCD x 32; nb fastest -> A panel + B slice stay per-XCD
  const int wg = blockIdx.x;
  const int id = (wg & 7) * 32 + (wg >> 3);
  const int nb = id & 7;    // N / 384
  const int mb = id >> 3;   // M / 128

  const int t = threadIdx.x;
  const int lane = t & 63;
  const int w = t >> 6;      // 0..7
  const int wr = w >> 2;     // 0..1 (M, 64 rows)
  const int wc = w & 3;      // 0..3 (N, 96 cols)
  const int lr = lane & 15;
  const int g4 = lane >> 4;  // 0..3

  const unsigned schunk = (((unsigned)(t & 7)) ^ ((unsigned)((t >> 3) & 7))) << 4;
  const char* Ag = (const char*)hiddenB + (size_t)(mb * BMT) * 2048;
  const char* Bg = (const char*)WT + (size_t)(nb * BNT) * 2048;

  // one issue = 64 rows x 128B = 8KB; thread t covers row (t>>3), chunk (t&7)
  auto stage = [&](const char* gb, int growbase, int kbyte, char* ldsdest) {
    gload_lds16(gb + (size_t)(growbase + (t >> 3)) * 2048 + kbyte + schunk,
                ldsdest + w * 1024);
  };
  // stage one full K-tile (A: 2 units, B: 6 units) = 8 gloads/thread
  auto stage_tile = [&](int kt, char* Sb) {
    const int kb = kt * 128;
    stage(Ag, 0, kb, Sb);
    stage(Ag, 64, kb, Sb + 8192);
#pragma unroll
    for (int i = 0; i < 6; ++i) stage(Bg, i * 64, kb, Sb + 16384 + i * 8192);
  };
  const unsigned axor = ((unsigned)(lr & 7)) << 4;

  f32x4 acc[4][6] = {};

  // prologue: stage tiles 0 and 1
  stage_tile(0, (char*)smem);
  stage_tile(1, (char*)smem + BUFBYTES);
  asm volatile("s_waitcnt vmcnt(8)" ::: "memory");  // tile 0 ready; tile 1 in flight
  __builtin_amdgcn_s_barrier();

  for (int j = 0; j < NTL; ++j) {
    const char* Ab = (const char*)smem + (j & 1) * BUFBYTES;
    const char* Bb = Ab + 16384;

    // ---- read ALL fragments of tile j into registers ----
    bf16x8 af[4][2], bfr[6][2];
#pragma unroll
    for (int mi = 0; mi < 4; ++mi)
#pragma unroll
      for (int ks = 0; ks < 2; ++ks)
        af[mi][ks] = *(const bf16x8*)(Ab + (size_t)(wr * 64 + mi * 16 + lr) * 128 +
                                      (((unsigned)(ks * 64 + g4 * 16)) ^ axor));
#pragma unroll
    for (int ni = 0; ni < 6; ++ni)
#pragma unroll
      for (int ks = 0; ks < 2; ++ks)
        bfr[ni][ks] = *(const bf16x8*)(Bb + (size_t)(wc * 96 + ni * 16 + lr) * 128 +
                                       (((unsigned)(ks * 64 + g4 * 16)) ^ axor));

    asm volatile("s_waitcnt lgkmcnt(0)" ::: "memory");
    __builtin_amdgcn_sched_barrier(0);
    __builtin_amdgcn_s_barrier();          // all waves done reading buf[j&1]

    if (j + 2 < NTL) stage_tile(j + 2, (char*)smem + (j & 1) * BUFBYTES);

    // ---- 48-MFMA burst ----
    __builtin_amdgcn_s_setprio(1);
#pragma unroll
    for (int mi = 0; mi < 4; ++mi)
#pragma unroll
      for (int ni = 0; ni < 6; ++ni)
#pragma unroll
        for (int ks = 0; ks < 2; ++ks)
          acc[mi][ni] = MFMA16(af[mi][ks], bfr[ni][ks], acc[mi][ni]);
    __builtin_amdgcn_s_setprio(0);

    if (j + 1 < NTL) {
      if (j + 2 < NTL)
        asm volatile("s_waitcnt vmcnt(8)" ::: "memory");  // stage(j+1) done; (j+2) in flight
      else
        asm volatile("s_waitcnt vmcnt(0)" ::: "memory");
      __builtin_amdgcn_s_barrier();
    }
  }

  // epilogue: bias + scatter; per 16-col chunk select z (chunks never straddle z)
#pragma unroll
  for (int ni = 0; ni < 6; ++ni) {
    int col = nb * BNT + wc * 96 + ni * 16 + lr;
    int z = col >> 10;
    int ci = col & 1023;
    const float* bias = (z == 0) ? bq : (z == 1) ? bk : bv;
    float bia = bias[ci];
    int hh = ci >> 6, d = ci & 63;
    if (z < 2) {
      bf16_t* Out = (z == 0) ? Qo : Ko;
#pragma unroll
      for (int mi = 0; mi < 4; ++mi) {
#pragma unroll
        for (int r = 0; r < 4; ++r) {
          int row = mb * BMT + wr * 64 + mi * 16 + g4 * 4 + r;
          int b = row >> 10, s = row & 1023;
          Out[((size_t)(b * NHEAD + hh) * SS + s) * HDIM + d] = (bf16_t)(acc[mi][ni][r] + bia);
        }
      }
    } else {
#pragma unroll
      for (int mi = 0; mi < 4; ++mi) {
        int row0 = mb * BMT + wr * 64 + mi * 16 + g4 * 4;
        int b = row0 >> 10, s0 = row0 & 1023;
        float v0 = acc[mi][ni][0] + bia, v1 = acc[mi][ni][1] + bia;
        float v2 = acc[mi][ni][2] + bia, v3 = acc[mi][ni][3] + bia;
        unsigned u0, u1;
        asm("v_cvt_pk_bf16_f32 %0, %1, %2" : "=v"(u0) : "v"(v0), "v"(v1));
        asm("v_cvt_pk_bf16_f32 %0, %1, %2" : "=v"(u1) : "v"(v2), "v"(v3));
        uint2 pv; pv.x = u0; pv.y = u1;
        *(uint2*)&Vt[((size_t)(b * NHEAD + hh) * HDIM + d) * SS + s0] = pv;
      }
    }
  }
}

// ---------------- fused flash attention v8: split-KV + fixed-offset softmax ----------------
__global__ __launch_bounds__(512, 4) void attn8_kernel(const bf16_t* __restrict__ Q,
                                                       const bf16_t* __restrict__ K,
                                                       const bf16_t* __restrict__ Vt,
                                                       const float* __restrict__ mask,
                                                       float* __restrict__ out) {
  __shared__ bf16_t KVsm[2][2][2][64 * 64];  // [half][buf][K/V][8KB] = 64 KB
  __shared__ float Msm[SS];                  // 4 KB

  const int wg = blockIdx.x;
  const int id = (wg & 7) * 64 + (wg >> 3);
  const int xblk = id & 7;
  const int bh = id >> 3;

  const int b = bh >> 4;
  const int h = bh & 15;
  const int t = threadIdx.x;
  const int lane = t & 63;
  const int w = t >> 6;        // 0..7
  const int wl = w & 3;        // q-group
  const int half = w >> 2;     // kv half
  const int l31 = lane & 31;
  const int hi = lane >> 5;
  const int q0 = xblk * 128 + wl * 32;
  const int kvbase = half * 512;

  const bf16_t* Qh = Q + (size_t)bh * SS * HDIM;
  const bf16_t* Kh = K + (size_t)bh * SS * HDIM;
  const bf16_t* Vh = Vt + (size_t)bh * HDIM * SS;  // [d][s]

  const float L2E = 1.4426950408889634f;
  if (t < 256) {
    float4 mv = *(const float4*)&mask[(size_t)b * SS + t * 4];
    mv.x = mv.x * L2E - 16.f; mv.y = mv.y * L2E - 16.f;
    mv.z = mv.z * L2E - 16.f; mv.w = mv.w * L2E - 16.f;
    *(float4*)&Msm[t * 4] = mv;
  }

  bf16x8 qb[4];
#pragma unroll
  for (int c = 0; c < 4; ++c) {
    bf16x8 q = *(const bf16x8*)&Qh[(size_t)(q0 + l31) * HDIM + c * 16 + hi * 8];
#pragma unroll
    for (int e = 0; e < 8; ++e) q[e] = (bf16_t)((float)q[e] * (0.125f * L2E));
    qb[c] = q;
  }

  const int srow = lane >> 3;
  const unsigned gcol = ((lane & 7) * 16) ^ (srow << 4);
  const unsigned swz = (unsigned)((l31 & 7) << 4);

  auto stageKV = [&](int tile, int buf) {
    const int kv0 = kvbase + tile * 64;
#pragma unroll
    for (int i = 0; i < 2; ++i) {
      int rbase = wl * 16 + i * 8;
      gload_lds16((const char*)Kh + (size_t)(kv0 + rbase + srow) * 128 + gcol,
                  (char*)&KVsm[half][buf][0][0] + (size_t)rbase * 128);
      gload_lds16((const char*)Vh + (size_t)(rbase + srow) * 2048 + (size_t)kv0 * 2 + gcol,
                  (char*)&KVsm[half][buf][1][0] + (size_t)rbase * 128);
    }
  };

  f32x16 acc0 = {}, acc1 = {};
  f32x8 la = {}, lb = {};  // deferred l accumulators

  stageKV(0, 0);
  asm volatile("s_waitcnt vmcnt(0) lgkmcnt(0)" ::: "memory");
  __builtin_amdgcn_s_barrier();

  for (int tt = 0; tt < 8; ++tt) {
    if (tt + 1 < 8) stageKV(tt + 1, (tt + 1) & 1);
    const char* Kb = (const char*)&KVsm[half][tt & 1][0][0];
    const char* Vb = (const char*)&KVsm[half][tt & 1][1][0];
    const int kv0 = kvbase + tt * 64;

    f32x16 st0 = {}, st1 = {};
    __builtin_amdgcn_s_setprio(1);
#pragma unroll
    for (int c = 0; c < 4; ++c) {
      bf16x8 kf0 = *(const bf16x8*)(Kb + (size_t)l31 * 128 + ((unsigned)(c * 32 + hi * 16) ^ swz));
      st0 = MFMA32(kf0, qb[c], st0);
    }
#pragma unroll
    for (int c = 0; c < 4; ++c) {
      bf16x8 kf1 = *(const bf16x8*)(Kb + (size_t)(32 + l31) * 128 + ((unsigned)(c * 32 + hi * 16) ^ swz));
      st1 = MFMA32(kf1, qb[c], st1);
    }
    __builtin_amdgcn_s_setprio(0);

#pragma unroll
    for (int k2 = 0; k2 < 8; ++k2) {
      int off = 8 * (k2 >> 1) + 4 * hi + 2 * (k2 & 1);
      float2 m0v = *(const float2*)&Msm[kv0 + off];
      float2 m1v = *(const float2*)&Msm[kv0 + 32 + off];
      st0[2 * k2] += m0v.x; st0[2 * k2 + 1] += m0v.y;
      st1[2 * k2] += m1v.x; st1[2 * k2 + 1] += m1v.y;
    }
#pragma unroll
    for (int r = 0; r < 16; ++r) st0[r] = EXP2(st0[r]);
#pragma unroll
    for (int r = 0; r < 16; ++r) st1[r] = EXP2(st1[r]);

#pragma unroll
    for (int r = 0; r < 8; ++r) {
      la[r] += st0[r] + st0[r + 8];
      lb[r] += st1[r] + st1[r + 8];
    }

    unsigned wd0[8], wd1[8];
#pragma unroll
    for (int k2 = 0; k2 < 8; ++k2) {
      unsigned r0, r1;
      float a0f = st0[2 * k2], a1f = st0[2 * k2 + 1];
      float b0f = st1[2 * k2], b1f = st1[2 * k2 + 1];
      asm("v_cvt_pk_bf16_f32 %0, %1, %2" : "=v"(r0) : "v"(a0f), "v"(a1f));
      asm("v_cvt_pk_bf16_f32 %0, %1, %2" : "=v"(r1) : "v"(b0f), "v"(b1f));
      wd0[k2] = r0; wd1[k2] = r1;
    }
    unsigned a0 = wd0[0], b0 = wd0[2]; PSWAP(a0, b0);
    unsigned a1 = wd0[1], b1 = wd0[3]; PSWAP(a1, b1);
    unsigned a2 = wd0[4], b2 = wd0[6]; PSWAP(a2, b2);
    unsigned a3 = wd0[5], b3 = wd0[7]; PSWAP(a3, b3);
    unsigned c0 = wd1[0], d0 = wd1[2]; PSWAP(c0, d0);
    unsigned c1 = wd1[1], d1 = wd1[3]; PSWAP(c1, d1);
    unsigned c2 = wd1[4], d2 = wd1[6]; PSWAP(c2, d2);
    unsigned c3 = wd1[5], d3 = wd1[7]; PSWAP(c3, d3);
    union { unsigned u[4]; bf16x8 v; } pf0, pf1, pf2, pf3;
    pf0.u[0] = a0; pf0.u[1] = a1; pf0.u[2] = b0; pf0.u[3] = b1;
    pf1.u[0] = a2; pf1.u[1] = a3; pf1.u[2] = b2; pf1.u[3] = b3;
    pf2.u[0] = c0; pf2.u[1] = c1; pf2.u[2] = d0; pf2.u[3] = d1;
    pf3.u[0] = c2; pf3.u[1] = c3; pf3.u[2] = d2; pf3.u[3] = d3;

    __builtin_amdgcn_s_setprio(1);
    {
      bf16x8 vf;
      vf = *(const bf16x8*)(Vb + (size_t)(l31) * 128 + ((unsigned)(0 * 32 + hi * 16) ^ swz));
      acc0 = MFMA32(vf, pf0.v, acc0);
      vf = *(const bf16x8*)(Vb + (size_t)(32 + l31) * 128 + ((unsigned)(0 * 32 + hi * 16) ^ swz));
      acc1 = MFMA32(vf, pf0.v, acc1);
      vf = *(const bf16x8*)(Vb + (size_t)(l31) * 128 + ((unsigned)(1 * 32 + hi * 16) ^ swz));
      acc0 = MFMA32(vf, pf1.v, acc0);
      vf = *(const bf16x8*)(Vb + (size_t)(32 + l31) * 128 + ((unsigned)(1 * 32 + hi * 16) ^ swz));
      acc1 = MFMA32(vf, pf1.v, acc1);
      vf = *(const bf16x8*)(Vb + (size_t)(l31) * 128 + ((unsigned)(2 * 32 + hi * 16) ^ swz));
      acc0 = MFMA32(vf, pf2.v, acc0);
      vf = *(const bf16x8*)(Vb + (size_t)(32 + l31) * 128 + ((unsigned)(2 * 32 + hi * 16) ^ swz));
      acc1 = MFMA32(vf, pf2.v, acc1);
      vf = *(const bf16x8*)(Vb + (size_t)(l31) * 128 + ((unsigned)(3 * 32 + hi * 16) ^ swz));
      acc0 = MFMA32(vf, pf3.v, acc0);
      vf = *(const bf16x8*)(Vb + (size_t)(32 + l31) * 128 + ((unsigned)(3 * 32 + hi * 16) ^ swz));
      acc1 = MFMA32(vf, pf3.v, acc1);
    }
    __builtin_amdgcn_s_setprio(0);

    asm volatile("s_waitcnt vmcnt(0)" ::: "memory");
    __builtin_amdgcn_s_barrier();
  }

  // ---- final l reduction (once) ----
  float l_run;
  {
    float s0 = (la[0] + lb[0]) + (la[1] + lb[1]);
    float s1 = (la[2] + lb[2]) + (la[3] + lb[3]);
    float s2 = (la[4] + lb[4]) + (la[5] + lb[5]);
    float s3 = (la[6] + lb[6]) + (la[7] + lb[7]);
    l_run = (s0 + s1) + (s2 + s3);
    l_run += __shfl_xor(l_run, 32);
  }

  // ---- split-KV merge via LDS (same offset both halves: O = (A0+A1)/(l0+l1)) ----
  __syncthreads();
  float* mb = (float*)&KVsm[0][0][0][0];
  if (half == 1) {
    float* dst = mb + ((size_t)(wl * 64 + lane)) * 36;
#pragma unroll
    for (int g = 0; g < 4; ++g) {
      float4 w0, w1;
      w0.x = acc0[g * 4 + 0]; w0.y = acc0[g * 4 + 1];
      w0.z = acc0[g * 4 + 2]; w0.w = acc0[g * 4 + 3];
      w1.x = acc1[g * 4 + 0]; w1.y = acc1[g * 4 + 1];
      w1.z = acc1[g * 4 + 2]; w1.w = acc1[g * 4 + 3];
      *(float4*)(dst + g * 4) = w0;
      *(float4*)(dst + 16 + g * 4) = w1;
    }
    dst[32] = l_run;
  }
  __syncthreads();
  if (half == 0) {
    const float* src = mb + ((size_t)(wl * 64 + lane)) * 36;
    float rinv = 1.0f / (l_run + src[32]);
    int q = q0 + l31;
    float* ob = out + ((size_t)(b * SS + q)) * HH + h * HDIM;
#pragma unroll
    for (int g = 0; g < 4; ++g) {
      float4 o0, o1;
      o0.x = (acc0[g * 4 + 0] + src[g * 4 + 0]) * rinv;
      o0.y = (acc0[g * 4 + 1] + src[g * 4 + 1]) * rinv;
      o0.z = (acc0[g * 4 + 2] + src[g * 4 + 2]) * rinv;
      o0.w = (acc0[g * 4 + 3] + src[g * 4 + 3]) * rinv;
      o1.x = (acc1[g * 4 + 0] + src[16 + g * 4 + 0]) * rinv;
      o1.y = (acc1[g * 4 + 1] + src[16 + g * 4 + 1]) * rinv;
      o1.z = (acc1[g * 4 + 2] + src[16 + g * 4 + 2]) * rinv;
      o1.w = (acc1[g * 4 + 3] + src[16 + g * 4 + 3]) * rinv;
      *(float4*)&ob[g * 8 + 4 * hi] = o0;
      *(float4*)&ob[32 + g * 8 + 4 * hi] = o1;
    }
  }
}

// ---------------- launch ----------------
extern "C" void kernel_launch(void* const* d_in, const int* in_sizes, int n_in,
                              void* d_out, int out_size, void* d_ws, size_t ws_size,
                              hipStream_t stream) {
  const float* hs   = (const float*)d_in[0];
  const float* mask = (const float*)d_in[1];
  const float* Wq   = (const float*)d_in[2];
  const float* bq   = (const float*)d_in[3];
  const float* Wk   = (const float*)d_in[4];
  const float* bk   = (const float*)d_in[5];
  const float* Wv   = (const float*)d_in[6];
  const float* bv   = (const float*)d_in[7];
  float* out = (float*)d_out;

  char* ws = (char*)d_ws;
  bf16_t* hiddenB = (bf16_t*)ws;                                  // 8 MB
  bf16_t* WT      = (bf16_t*)(ws + (size_t)8 * 1024 * 1024);      // 6 MB
  bf16_t* Qb      = (bf16_t*)(ws + (size_t)14 * 1024 * 1024);     // 8 MB
  bf16_t* Kb      = (bf16_t*)(ws + (size_t)22 * 1024 * 1024);     // 8 MB
  bf16_t* Vt      = (bf16_t*)(ws + (size_t)30 * 1024 * 1024);     // 8 MB

  prep_kernel<<<2048 + 3072, 256, 0, stream>>>(hs, Wq, Wk, Wv, hiddenB, WT);
  qkv_gemm3<<<256, 512, 0, stream>>>(hiddenB, WT, bq, bk, bv, Qb, Kb, Vt);
  attn8_kernel<<<512, 512, 0, stream>>>(Qb, Kb, Vt, mask, out);
}

// Round 13
// 70.789 us; speedup vs baseline: 1.0459x; 1.0459x over previous
//
#include <hip/hip_runtime.h>
#include <hip/hip_bf16.h>

typedef __bf16 bf16_t;
typedef __bf16 bf16x8 __attribute__((ext_vector_type(8)));
typedef float f32x4 __attribute__((ext_vector_type(4)));
typedef float f32x8 __attribute__((ext_vector_type(8)));
typedef float f32x16 __attribute__((ext_vector_type(16)));
typedef unsigned uint2v __attribute__((ext_vector_type(2)));

#define MFMA16(a, b, c) __builtin_amdgcn_mfma_f32_16x16x32_bf16((a), (b), (c), 0, 0, 0)
#define MFMA32(a, b, c) __builtin_amdgcn_mfma_f32_32x32x16_bf16((a), (b), (c), 0, 0, 0)

static constexpr int BB = 4, SS = 1024, HH = 1024, NHEAD = 16, HDIM = 64;
static constexpr int MM = BB * SS;  // 4096

__device__ __forceinline__ void gload_lds16(const void* g, void* l) {
  __builtin_amdgcn_global_load_lds((const __attribute__((address_space(1))) void*)g,
                                   (__attribute__((address_space(3))) void*)l, 16, 0, 0);
}

#if __has_builtin(__builtin_amdgcn_permlane32_swap)
#define PSWAP(a, b)                                                    \
  {                                                                    \
    uint2v _r = __builtin_amdgcn_permlane32_swap((a), (b), false, false); \
    (a) = _r.x;                                                        \
    (b) = _r.y;                                                        \
  }
#else
#define PSWAP(a, b) asm("v_permlane32_swap_b32 %0, %1" : "+v"(a), "+v"(b))
#endif

__device__ __forceinline__ float EXP2(float x) {
  float r;
  asm("v_exp_f32 %0, %1" : "=v"(r) : "v"(x));
  return r;
}

// ---------------- prep: fp32->bf16 cvt (hidden) + W transpose, one launch ----------------
__global__ __launch_bounds__(256) void prep_kernel(const float* __restrict__ hs,
                                                   const float* __restrict__ Wq,
                                                   const float* __restrict__ Wk,
                                                   const float* __restrict__ Wv,
                                                   bf16_t* __restrict__ hiddenB,
                                                   bf16_t* __restrict__ WT) {
  const int t = threadIdx.x;
  if (blockIdx.x < 2048) {
    int i = (blockIdx.x * 256 + t) * 8;
    float4 a = *(const float4*)(hs + i);
    float4 b = *(const float4*)(hs + i + 4);
    union { int4 i4; bf16_t h[8]; } u;
    u.h[0] = (bf16_t)a.x; u.h[1] = (bf16_t)a.y; u.h[2] = (bf16_t)a.z; u.h[3] = (bf16_t)a.w;
    u.h[4] = (bf16_t)b.x; u.h[5] = (bf16_t)b.y; u.h[6] = (bf16_t)b.z; u.h[7] = (bf16_t)b.w;
    *(int4*)(hiddenB + i) = u.i4;
  } else {
    __shared__ float tile[32][33];
    int id = blockIdx.x - 2048;       // 0..3071
    int z = id >> 10;                 // 0..2
    int rem = id & 1023;
    int bx = rem & 31, by = rem >> 5;
    const float* W = (z == 0) ? Wq : (z == 1) ? Wk : Wv;
    bf16_t* Out = WT + (size_t)z * HH * HH;
    int tx = t & 31, ty = t >> 5;     // 32 x 8
    int x0 = bx * 32;                 // n
    int y0 = by * 32;                 // k
    for (int j = ty; j < 32; j += 8)
      tile[j][tx] = W[(size_t)(y0 + j) * HH + x0 + tx];
    __syncthreads();
    for (int j = ty; j < 32; j += 8)
      Out[(size_t)(x0 + j) * HH + y0 + tx] = (bf16_t)tile[tx][j];
  }
}

// ---------------- QKV GEMM v5: phased counted-vmcnt pipeline ----------------
// BM=128 x BN=384, BK=64, 256 blocks (1/CU), 8 waves (2M x 4N).
// Phase-p B-columns remapped: wave wc covers cols p*128 + wc*32 (+ni*16), so phase
// p's reads exactly cover LDS B rows [128p,128p+128). After each phase's
// lgkmcnt(0)+barrier that region of the CURRENT buffer is dead block-wide ->
// stage tile j+2's matching units into it (A+B01 after ph0, B23 after ph1,
// B45 after ph2). End of tile: vmcnt(8) -- tile j+1 landed, tile j+2's 8 loads
// remain in flight across the barrier (never drained mid-loop).
#define BMT 128
#define BNT 384
#define BKT 64
#define NTL 16
#define BUFBYTES 65536  // (128+384)*64*2

__global__ __launch_bounds__(512, 2) void qkv_gemm5(const bf16_t* __restrict__ hiddenB,
                                                    const bf16_t* __restrict__ WT,
                                                    const float* __restrict__ bq,
                                                    const float* __restrict__ bk,
                                                    const float* __restrict__ bv,
                                                    bf16_t* __restrict__ Qo,
                                                    bf16_t* __restrict__ Ko,
                                                    bf16_t* __restrict__ Vt) {
  __shared__ bf16_t smem[2 * BUFBYTES / 2];  // 128 KB

  // XCD swizzle: 256 wgs = 8 XCD x 32; nb fastest -> A panel + B slice stay per-XCD
  const int wg = blockIdx.x;
  const int id = (wg & 7) * 32 + (wg >> 3);
  const int nb = id & 7;    // N / 384
  const int mb = id >> 3;   // M / 128

  const int t = threadIdx.x;
  const int lane = t & 63;
  const int w = t >> 6;      // 0..7
  const int wr = w >> 2;     // 0..1 (M, 64 rows)
  const int wc = w & 3;      // 0..3 (N, 32-col slice per phase)
  const int lr = lane & 15;
  const int g4 = lane >> 4;  // 0..3

  const unsigned schunk = (((unsigned)(t & 7)) ^ ((unsigned)((t >> 3) & 7))) << 4;
  const char* Ag = (const char*)hiddenB + (size_t)(mb * BMT) * 2048;
  const char* Bg = (const char*)WT + (size_t)(nb * BNT) * 2048;

  // one issue = 64 rows x 128B = 8KB; thread t covers row (t>>3), chunk (t&7)
  auto stage = [&](const char* gb, int growbase, int kbyte, char* ldsdest) {
    gload_lds16(gb + (size_t)(growbase + (t >> 3)) * 2048 + kbyte + schunk,
                ldsdest + w * 1024);
  };
  const unsigned axor = ((unsigned)(lr & 7)) << 4;

  auto rdA = [&](const char* Ab, int mi, int ks) -> bf16x8 {
    return *(const bf16x8*)(Ab + (size_t)(wr * 64 + mi * 16 + lr) * 128 +
                            (((unsigned)(ks * 64 + g4 * 16)) ^ axor));
  };
  auto rdB = [&](const char* Bb, int p, int ni, int ks) -> bf16x8 {
    return *(const bf16x8*)(Bb + (size_t)(p * 128 + wc * 32 + ni * 16 + lr) * 128 +
                            (((unsigned)(ks * 64 + g4 * 16)) ^ axor));
  };

  f32x4 acc[4][6] = {};

  // prologue: stage tiles 0 and 1 (8 loads each)
  {
    char* S0 = (char*)smem;
    stage(Ag, 0, 0, S0); stage(Ag, 64, 0, S0 + 8192);
#pragma unroll
    for (int i = 0; i < 6; ++i) stage(Bg, i * 64, 0, S0 + 16384 + i * 8192);
    char* S1 = (char*)smem + BUFBYTES;
    stage(Ag, 0, 128, S1); stage(Ag, 64, 128, S1 + 8192);
#pragma unroll
    for (int i = 0; i < 6; ++i) stage(Bg, i * 64, 128, S1 + 16384 + i * 8192);
  }
  asm volatile("s_waitcnt vmcnt(8)" ::: "memory");  // tile 0 ready; tile 1 in flight
  __builtin_amdgcn_s_barrier();

  for (int j = 0; j < NTL; ++j) {
    const char* Ab = (const char*)smem + (j & 1) * BUFBYTES;
    const char* Bb = Ab + 16384;
    char* Sb = (char*)smem + (j & 1) * BUFBYTES;  // stage j+2 into just-freed regions
    const bool st = (j + 2 < NTL);
    const int kb2 = (j + 2) * 128;

    // ---- phase 0: A-frags + B cols [0,128) ----
    bf16x8 af[4][2], b0[2][2];
#pragma unroll
    for (int mi = 0; mi < 4; ++mi)
#pragma unroll
      for (int ks = 0; ks < 2; ++ks) af[mi][ks] = rdA(Ab, mi, ks);
#pragma unroll
    for (int ni = 0; ni < 2; ++ni)
#pragma unroll
      for (int ks = 0; ks < 2; ++ks) b0[ni][ks] = rdB(Bb, 0, ni, ks);
    asm volatile("s_waitcnt lgkmcnt(0)" ::: "memory");
    __builtin_amdgcn_s_barrier();  // A region + B rows [0,128) free block-wide
    if (st) {
      stage(Ag, 0, kb2, Sb); stage(Ag, 64, kb2, Sb + 8192);
      stage(Bg, 0, kb2, Sb + 16384); stage(Bg, 64, kb2, Sb + 16384 + 8192);
    }
    __builtin_amdgcn_s_setprio(1);
#pragma unroll
    for (int mi = 0; mi < 4; ++mi)
#pragma unroll
      for (int ni = 0; ni < 2; ++ni)
#pragma unroll
        for (int ks = 0; ks < 2; ++ks)
          acc[mi][ni] = MFMA16(af[mi][ks], b0[ni][ks], acc[mi][ni]);
    __builtin_amdgcn_s_setprio(0);

    // ---- phase 1: B cols [128,256) ----
    bf16x8 b1[2][2];
#pragma unroll
    for (int ni = 0; ni < 2; ++ni)
#pragma unroll
      for (int ks = 0; ks < 2; ++ks) b1[ni][ks] = rdB(Bb, 1, ni, ks);
    asm volatile("s_waitcnt lgkmcnt(0)" ::: "memory");
    __builtin_amdgcn_s_barrier();  // B rows [128,256) free
    if (st) {
      stage(Bg, 128, kb2, Sb + 16384 + 2 * 8192);
      stage(Bg, 192, kb2, Sb + 16384 + 3 * 8192);
    }
    __builtin_amdgcn_s_setprio(1);
#pragma unroll
    for (int mi = 0; mi < 4; ++mi)
#pragma unroll
      for (int ni = 0; ni < 2; ++ni)
#pragma unroll
        for (int ks = 0; ks < 2; ++ks)
          acc[mi][2 + ni] = MFMA16(af[mi][ks], b1[ni][ks], acc[mi][2 + ni]);
    __builtin_amdgcn_s_setprio(0);

    // ---- phase 2: B cols [256,384) ----
    bf16x8 b2[2][2];
#pragma unroll
    for (int ni = 0; ni < 2; ++ni)
#pragma unroll
      for (int ks = 0; ks < 2; ++ks) b2[ni][ks] = rdB(Bb, 2, ni, ks);
    asm volatile("s_waitcnt lgkmcnt(0)" ::: "memory");
    __builtin_amdgcn_s_barrier();  // B rows [256,384) free
    if (st) {
      stage(Bg, 256, kb2, Sb + 16384 + 4 * 8192);
      stage(Bg, 320, kb2, Sb + 16384 + 5 * 8192);
    }
    __builtin_amdgcn_s_setprio(1);
#pragma unroll
    for (int mi = 0; mi < 4; ++mi)
#pragma unroll
      for (int ni = 0; ni < 2; ++ni)
#pragma unroll
        for (int ks = 0; ks < 2; ++ks)
          acc[mi][4 + ni] = MFMA16(af[mi][ks], b2[ni][ks], acc[mi][4 + ni]);
    __builtin_amdgcn_s_setprio(0);

    // ---- end of tile: counted wait (tile j+1 landed; j+2 stays in flight) ----
    if (j + 1 < NTL) {
      if (st)
        asm volatile("s_waitcnt vmcnt(8)" ::: "memory");
      else
        asm volatile("s_waitcnt vmcnt(0)" ::: "memory");
      __builtin_amdgcn_s_barrier();
    }
  }

  // epilogue: bias + scatter; acc[mi][2p+ni] -> col = nb*384 + p*128 + wc*32 + ni*16 + lr
#pragma unroll
  for (int ni6 = 0; ni6 < 6; ++ni6) {
    int p = ni6 >> 1, ni = ni6 & 1;
    int col = nb * BNT + p * 128 + wc * 32 + ni * 16 + lr;
    int z = col >> 10;
    int ci = col & 1023;
    const float* bias = (z == 0) ? bq : (z == 1) ? bk : bv;
    float bia = bias[ci];
    int hh = ci >> 6, d = ci & 63;
    if (z < 2) {
      bf16_t* Out = (z == 0) ? Qo : Ko;
#pragma unroll
      for (int mi = 0; mi < 4; ++mi) {
#pragma unroll
        for (int r = 0; r < 4; ++r) {
          int row = mb * BMT + wr * 64 + mi * 16 + g4 * 4 + r;
          int b = row >> 10, s = row & 1023;
          Out[((size_t)(b * NHEAD + hh) * SS + s) * HDIM + d] = (bf16_t)(acc[mi][ni6][r] + bia);
        }
      }
    } else {
#pragma unroll
      for (int mi = 0; mi < 4; ++mi) {
        int row0 = mb * BMT + wr * 64 + mi * 16 + g4 * 4;
        int b = row0 >> 10, s0 = row0 & 1023;
        float v0 = acc[mi][ni6][0] + bia, v1 = acc[mi][ni6][1] + bia;
        float v2 = acc[mi][ni6][2] + bia, v3 = acc[mi][ni6][3] + bia;
        unsigned u0, u1;
        asm("v_cvt_pk_bf16_f32 %0, %1, %2" : "=v"(u0) : "v"(v0), "v"(v1));
        asm("v_cvt_pk_bf16_f32 %0, %1, %2" : "=v"(u1) : "v"(v2), "v"(v3));
        uint2 pv; pv.x = u0; pv.y = u1;
        *(uint2*)&Vt[((size_t)(b * NHEAD + hh) * HDIM + d) * SS + s0] = pv;
      }
    }
  }
}

// ---------------- fused flash attention v8: split-KV + fixed-offset softmax ----------------
__global__ __launch_bounds__(512, 4) void attn8_kernel(const bf16_t* __restrict__ Q,
                                                       const bf16_t* __restrict__ K,
                                                       const bf16_t* __restrict__ Vt,
                                                       const float* __restrict__ mask,
                                                       float* __restrict__ out) {
  __shared__ bf16_t KVsm[2][2][2][64 * 64];  // [half][buf][K/V][8KB] = 64 KB
  __shared__ float Msm[SS];                  // 4 KB

  const int wg = blockIdx.x;
  const int id = (wg & 7) * 64 + (wg >> 3);
  const int xblk = id & 7;
  const int bh = id >> 3;

  const int b = bh >> 4;
  const int h = bh & 15;
  const int t = threadIdx.x;
  const int lane = t & 63;
  const int w = t >> 6;        // 0..7
  const int wl = w & 3;        // q-group
  const int half = w >> 2;     // kv half
  const int l31 = lane & 31;
  const int hi = lane >> 5;
  const int q0 = xblk * 128 + wl * 32;
  const int kvbase = half * 512;

  const bf16_t* Qh = Q + (size_t)bh * SS * HDIM;
  const bf16_t* Kh = K + (size_t)bh * SS * HDIM;
  const bf16_t* Vh = Vt + (size_t)bh * HDIM * SS;  // [d][s]

  const float L2E = 1.4426950408889634f;
  if (t < 256) {
    float4 mv = *(const float4*)&mask[(size_t)b * SS + t * 4];
    mv.x = mv.x * L2E - 16.f; mv.y = mv.y * L2E - 16.f;
    mv.z = mv.z * L2E - 16.f; mv.w = mv.w * L2E - 16.f;
    *(float4*)&Msm[t * 4] = mv;
  }

  bf16x8 qb[4];
#pragma unroll
  for (int c = 0; c < 4; ++c) {
    bf16x8 q = *(const bf16x8*)&Qh[(size_t)(q0 + l31) * HDIM + c * 16 + hi * 8];
#pragma unroll
    for (int e = 0; e < 8; ++e) q[e] = (bf16_t)((float)q[e] * (0.125f * L2E));
    qb[c] = q;
  }

  const int srow = lane >> 3;
  const unsigned gcol = ((lane & 7) * 16) ^ (srow << 4);
  const unsigned swz = (unsigned)((l31 & 7) << 4);

  auto stageKV = [&](int tile, int buf) {
    const int kv0 = kvbase + tile * 64;
#pragma unroll
    for (int i = 0; i < 2; ++i) {
      int rbase = wl * 16 + i * 8;
      gload_lds16((const char*)Kh + (size_t)(kv0 + rbase + srow) * 128 + gcol,
                  (char*)&KVsm[half][buf][0][0] + (size_t)rbase * 128);
      gload_lds16((const char*)Vh + (size_t)(rbase + srow) * 2048 + (size_t)kv0 * 2 + gcol,
                  (char*)&KVsm[half][buf][1][0] + (size_t)rbase * 128);
    }
  };

  f32x16 acc0 = {}, acc1 = {};
  f32x8 la = {}, lb = {};  // deferred l accumulators

  stageKV(0, 0);
  asm volatile("s_waitcnt vmcnt(0) lgkmcnt(0)" ::: "memory");
  __builtin_amdgcn_s_barrier();

  for (int tt = 0; tt < 8; ++tt) {
    if (tt + 1 < 8) stageKV(tt + 1, (tt + 1) & 1);
    const char* Kb = (const char*)&KVsm[half][tt & 1][0][0];
    const char* Vb = (const char*)&KVsm[half][tt & 1][1][0];
    const int kv0 = kvbase + tt * 64;

    f32x16 st0 = {}, st1 = {};
    __builtin_amdgcn_s_setprio(1);
#pragma unroll
    for (int c = 0; c < 4; ++c) {
      bf16x8 kf0 = *(const bf16x8*)(Kb + (size_t)l31 * 128 + ((unsigned)(c * 32 + hi * 16) ^ swz));
      st0 = MFMA32(kf0, qb[c], st0);
    }
#pragma unroll
    for (int c = 0; c < 4; ++c) {
      bf16x8 kf1 = *(const bf16x8*)(Kb + (size_t)(32 + l31) * 128 + ((unsigned)(c * 32 + hi * 16) ^ swz));
      st1 = MFMA32(kf1, qb[c], st1);
    }
    __builtin_amdgcn_s_setprio(0);

#pragma unroll
    for (int k2 = 0; k2 < 8; ++k2) {
      int off = 8 * (k2 >> 1) + 4 * hi + 2 * (k2 & 1);
      float2 m0v = *(const float2*)&Msm[kv0 + off];
      float2 m1v = *(const float2*)&Msm[kv0 + 32 + off];
      st0[2 * k2] += m0v.x; st0[2 * k2 + 1] += m0v.y;
      st1[2 * k2] += m1v.x; st1[2 * k2 + 1] += m1v.y;
    }
#pragma unroll
    for (int r = 0; r < 16; ++r) st0[r] = EXP2(st0[r]);
#pragma unroll
    for (int r = 0; r < 16; ++r) st1[r] = EXP2(st1[r]);

#pragma unroll
    for (int r = 0; r < 8; ++r) {
      la[r] += st0[r] + st0[r + 8];
      lb[r] += st1[r] + st1[r + 8];
    }

    unsigned wd0[8], wd1[8];
#pragma unroll
    for (int k2 = 0; k2 < 8; ++k2) {
      unsigned r0, r1;
      float a0f = st0[2 * k2], a1f = st0[2 * k2 + 1];
      float b0f = st1[2 * k2], b1f = st1[2 * k2 + 1];
      asm("v_cvt_pk_bf16_f32 %0, %1, %2" : "=v"(r0) : "v"(a0f), "v"(a1f));
      asm("v_cvt_pk_bf16_f32 %0, %1, %2" : "=v"(r1) : "v"(b0f), "v"(b1f));
      wd0[k2] = r0; wd1[k2] = r1;
    }
    unsigned a0 = wd0[0], b0 = wd0[2]; PSWAP(a0, b0);
    unsigned a1 = wd0[1], b1 = wd0[3]; PSWAP(a1, b1);
    unsigned a2 = wd0[4], b2 = wd0[6]; PSWAP(a2, b2);
    unsigned a3 = wd0[5], b3 = wd0[7]; PSWAP(a3, b3);
    unsigned c0 = wd1[0], d0 = wd1[2]; PSWAP(c0, d0);
    unsigned c1 = wd1[1], d1 = wd1[3]; PSWAP(c1, d1);
    unsigned c2 = wd1[4], d2 = wd1[6]; PSWAP(c2, d2);
    unsigned c3 = wd1[5], d3 = wd1[7]; PSWAP(c3, d3);
    union { unsigned u[4]; bf16x8 v; } pf0, pf1, pf2, pf3;
    pf0.u[0] = a0; pf0.u[1] = a1; pf0.u[2] = b0; pf0.u[3] = b1;
    pf1.u[0] = a2; pf1.u[1] = a3; pf1.u[2] = b2; pf1.u[3] = b3;
    pf2.u[0] = c0; pf2.u[1] = c1; pf2.u[2] = d0; pf2.u[3] = d1;
    pf3.u[0] = c2; pf3.u[1] = c3; pf3.u[2] = d2; pf3.u[3] = d3;

    __builtin_amdgcn_s_setprio(1);
    {
      bf16x8 vf;
      vf = *(const bf16x8*)(Vb + (size_t)(l31) * 128 + ((unsigned)(0 * 32 + hi * 16) ^ swz));
      acc0 = MFMA32(vf, pf0.v, acc0);
      vf = *(const bf16x8*)(Vb + (size_t)(32 + l31) * 128 + ((unsigned)(0 * 32 + hi * 16) ^ swz));
      acc1 = MFMA32(vf, pf0.v, acc1);
      vf = *(const bf16x8*)(Vb + (size_t)(l31) * 128 + ((unsigned)(1 * 32 + hi * 16) ^ swz));
      acc0 = MFMA32(vf, pf1.v, acc0);
      vf = *(const bf16x8*)(Vb + (size_t)(32 + l31) * 128 + ((unsigned)(1 * 32 + hi * 16) ^ swz));
      acc1 = MFMA32(vf, pf1.v, acc1);
      vf = *(const bf16x8*)(Vb + (size_t)(l31) * 128 + ((unsigned)(2 * 32 + hi * 16) ^ swz));
      acc0 = MFMA32(vf, pf2.v, acc0);
      vf = *(const bf16x8*)(Vb + (size_t)(32 + l31) * 128 + ((unsigned)(2 * 32 + hi * 16) ^ swz));
      acc1 = MFMA32(vf, pf2.v, acc1);
      vf = *(const bf16x8*)(Vb + (size_t)(l31) * 128 + ((unsigned)(3 * 32 + hi * 16) ^ swz));
      acc0 = MFMA32(vf, pf3.v, acc0);
      vf = *(const bf16x8*)(Vb + (size_t)(32 + l31) * 128 + ((unsigned)(3 * 32 + hi * 16) ^ swz));
      acc1 = MFMA32(vf, pf3.v, acc1);
    }
    __builtin_amdgcn_s_setprio(0);

    asm volatile("s_waitcnt vmcnt(0)" ::: "memory");
    __builtin_amdgcn_s_barrier();
  }

  // ---- final l reduction (once) ----
  float l_run;
  {
    float s0 = (la[0] + lb[0]) + (la[1] + lb[1]);
    float s1 = (la[2] + lb[2]) + (la[3] + lb[3]);
    float s2 = (la[4] + lb[4]) + (la[5] + lb[5]);
    float s3 = (la[6] + lb[6]) + (la[7] + lb[7]);
    l_run = (s0 + s1) + (s2 + s3);
    l_run += __shfl_xor(l_run, 32);
  }

  // ---- split-KV merge via LDS (same offset both halves: O = (A0+A1)/(l0+l1)) ----
  __syncthreads();
  float* mb = (float*)&KVsm[0][0][0][0];
  if (half == 1) {
    float* dst = mb + ((size_t)(wl * 64 + lane)) * 36;
#pragma unroll
    for (int g = 0; g < 4; ++g) {
      float4 w0, w1;
      w0.x = acc0[g * 4 + 0]; w0.y = acc0[g * 4 + 1];
      w0.z = acc0[g * 4 + 2]; w0.w = acc0[g * 4 + 3];
      w1.x = acc1[g * 4 + 0]; w1.y = acc1[g * 4 + 1];
      w1.z = acc1[g * 4 + 2]; w1.w = acc1[g * 4 + 3];
      *(float4*)(dst + g * 4) = w0;
      *(float4*)(dst + 16 + g * 4) = w1;
    }
    dst[32] = l_run;
  }
  __syncthreads();
  if (half == 0) {
    const float* src = mb + ((size_t)(wl * 64 + lane)) * 36;
    float rinv = 1.0f / (l_run + src[32]);
    int q = q0 + l31;
    float* ob = out + ((size_t)(b * SS + q)) * HH + h * HDIM;
#pragma unroll
    for (int g = 0; g < 4; ++g) {
      float4 o0, o1;
      o0.x = (acc0[g * 4 + 0] + src[g * 4 + 0]) * rinv;
      o0.y = (acc0[g * 4 + 1] + src[g * 4 + 1]) * rinv;
      o0.z = (acc0[g * 4 + 2] + src[g * 4 + 2]) * rinv;
      o0.w = (acc0[g * 4 + 3] + src[g * 4 + 3]) * rinv;
      o1.x = (acc1[g * 4 + 0] + src[16 + g * 4 + 0]) * rinv;
      o1.y = (acc1[g * 4 + 1] + src[16 + g * 4 + 1]) * rinv;
      o1.z = (acc1[g * 4 + 2] + src[16 + g * 4 + 2]) * rinv;
      o1.w = (acc1[g * 4 + 3] + src[16 + g * 4 + 3]) * rinv;
      *(float4*)&ob[g * 8 + 4 * hi] = o0;
      *(float4*)&ob[32 + g * 8 + 4 * hi] = o1;
    }
  }
}

// ---------------- launch ----------------
extern "C" void kernel_launch(void* const* d_in, const int* in_sizes, int n_in,
                              void* d_out, int out_size, void* d_ws, size_t ws_size,
                              hipStream_t stream) {
  const float* hs   = (const float*)d_in[0];
  const float* mask = (const float*)d_in[1];
  const float* Wq   = (const float*)d_in[2];
  const float* bq   = (const float*)d_in[3];
  const float* Wk   = (const float*)d_in[4];
  const float* bk   = (const float*)d_in[5];
  const float* Wv   = (const float*)d_in[6];
  const float* bv   = (const float*)d_in[7];
  float* out = (float*)d_out;

  char* ws = (char*)d_ws;
  bf16_t* hiddenB = (bf16_t*)ws;                                  // 8 MB
  bf16_t* WT      = (bf16_t*)(ws + (size_t)8 * 1024 * 1024);      // 6 MB
  bf16_t* Qb      = (bf16_t*)(ws + (size_t)14 * 1024 * 1024);     // 8 MB
  bf16_t* Kb      = (bf16_t*)(ws + (size_t)22 * 1024 * 1024);     // 8 MB
  bf16_t* Vt      = (bf16_t*)(ws + (size_t)30 * 1024 * 1024);     // 8 MB

  prep_kernel<<<2048 + 3072, 256, 0, stream>>>(hs, Wq, Wk, Wv, hiddenB, WT);
  qkv_gemm5<<<256, 512, 0, stream>>>(hiddenB, WT, bq, bk, bv, Qb, Kb, Vt);
  attn8_kernel<<<512, 512, 0, stream>>>(Qb, Kb, Vt, mask, out);
}